// Round 4
// baseline (1269.347 us; speedup 1.0000x reference)
//
#include <hip/hip_runtime.h>

// Shapes (fixed for this problem)
#define D_DIM 1024
#define S_DIM 2048
#define B_DIM 4
#define M_DIM 4096
#define NTOK  8192   // B*S

typedef unsigned short u16;
typedef __attribute__((ext_vector_type(8))) short short8;  // 8 bf16 (guide-verified frag type)
typedef __attribute__((ext_vector_type(4))) float fx4;

static __device__ __forceinline__ float b2f(u16 u) {
  union { unsigned int i; float f; } v; v.i = ((unsigned int)u) << 16; return v.f;
}
static __device__ __forceinline__ u16 f2b(float f) {
  union { float f; unsigned int i; } v; v.f = f;
  unsigned int r = v.i + 0x7fffu + ((v.i >> 16) & 1u); // RNE
  return (u16)(r >> 16);
}
// async global->LDS DMA, 16B per lane
static __device__ __forceinline__ void async16(u16* lds, const u16* g) {
  __builtin_amdgcn_global_load_lds(
      (__attribute__((address_space(1))) void*)(u16*)g,
      (__attribute__((address_space(3))) void*)lds, 16, 0, 0);
}

// ---------------- canary: prefill fp32 output with 1.0 (diagnostic) ----------------
__global__ void canary_kernel(float* __restrict__ out) {
  const long i = ((long)blockIdx.x * 256 + threadIdx.x) * 4;
  float4 v = {1.0f, 1.0f, 1.0f, 1.0f};
  *(float4*)(out + i) = v;
}

// ---------------- embedding gather + positional encoding (fp32 in, bf16 out) ----------------
__global__ void Transformer_33792802685820_kernel(
    const int* __restrict__ x, const float* __restrict__ emb,
    const float* __restrict__ pe, u16* __restrict__ h) {
  const int t = blockIdx.x;          // token index 0..NTOK-1
  const int s = t & (S_DIM - 1);     // position within sequence
  const int row = x[t];
  const int d = threadIdx.x * 4;     // 256 threads * 4 = 1024 = D
  float4 e = *(const float4*)(emb + (long)row * D_DIM + d);
  float4 p = *(const float4*)(pe + (long)s * D_DIM + d);
  ushort4 o;
  o.x = f2b(e.x + p.x);
  o.y = f2b(e.y + p.y);
  o.z = f2b(e.z + p.z);
  o.w = f2b(e.w + p.w);
  *(ushort4*)(h + (long)t * D_DIM + d) = o;
}

// ---------------- transpose fp32 -> bf16: out[C][R] = in[R][C] ----------------
__global__ void transpose_f_kernel(
    const float* __restrict__ in, u16* __restrict__ out, int R, int C) {
  __shared__ float tile[32][33];
  const int c0 = blockIdx.x * 32, r0 = blockIdx.y * 32;
  const int tx = threadIdx.x, ty = threadIdx.y; // 32 x 8
  for (int i = ty; i < 32; i += 8)
    tile[i][tx] = in[(long)(r0 + i) * C + (c0 + tx)];
  __syncthreads();
  for (int i = ty; i < 32; i += 8)
    out[(long)(c0 + i) * R + (r0 + tx)] = f2b(tile[tx][i]);
}

// ---------------- transpose bf16 -> bf16, batched over z ----------------
__global__ void transpose_b_kernel(
    const u16* __restrict__ in, u16* __restrict__ out, int R, int C) {
  __shared__ u16 tile[32][33];
  const long zoff = (long)blockIdx.z * R * C;
  const int c0 = blockIdx.x * 32, r0 = blockIdx.y * 32;
  const int tx = threadIdx.x, ty = threadIdx.y; // 32 x 8
  for (int i = ty; i < 32; i += 8)
    tile[i][tx] = in[zoff + (long)(r0 + i) * C + (c0 + tx)];
  __syncthreads();
  for (int i = ty; i < 32; i += 8)
    out[zoff + (long)(c0 + i) * R + (r0 + tx)] = tile[tx][i];
}

// ---------------- 256xBN MFMA GEMM v3: 1 barrier + 1 vmcnt per K-tile ----------------
// C = act(scale*A@Bt^T + bias). A [M,K], Bt [N,K] bf16 row-major; M %256==0,
// N %BN==0, K %128==0, per-z nwg %8==0. 512 thr = 8 waves (WMxWN), BN=256: 2x4
// (wave out 128x64), BN=128: 4x2 (wave out 64x64).
// KEY FIX vs r1/r3: four DISTINCT __shared__ objects (sA0/sA1/sB0/sB1) + K-loop
// unrolled x2 with LITERAL buffer identities. LLVM's waitcnt pass treats
// global_load_lds as a VMEM-write-to-LDS and inserts a conservative vmcnt drain
// before any ds_read that MAY alias an outstanding DMA dest; runtime-indexed
// sA[b] vs sA[b^1] is MayAlias -> full drain every phase (the r1/r3 ~1600cyc/
// phase stall). Distinct objects are NoAlias -> reads of buf0 proceed while
// buf1's DMAs are in flight.
// Schedule per K-tile (half of unrolled iter): issue ALL next-tile DMAs (6-8
// global_load_lds, ~8KB each) up front -> ds_read+MFMA the current buffer
// (waves drift freely, LDS pipe overlaps MFMA pipe; setprio favors MFMA) ->
// one vmcnt(0) (drains only next-tile loads, which had the whole tile to land)
// -> one barrier. Writes only touch the non-read buffer => no intra-tile WAR.
// LDS layout: per buffer, 4 (A) / BN/64 (B) issue-blocks of [64 rows][64 K],
// 16B-chunk swizzle phys = log ^ (row&7) (8-way bank spread); DMA source
// pre-swizzled, reads XOR (rule 21: linear dest + inverse-swizzled source).
template<int BN, bool RELU, bool BIAS, bool OUTF32>
__global__ __launch_bounds__(512) void gemm256(
    const u16* __restrict__ A, const u16* __restrict__ Bt,
    const float* __restrict__ bias, u16* __restrict__ C, float* __restrict__ Cf,
    int M, int N, int K, float scale, long sA_, long sB_, long sC_) {
  static_assert(BN == 256 || BN == 128, "BN");
  constexpr int WN   = BN / 64;        // waves in N: 4 or 2
  constexpr int WM   = 8 / WN;         // waves in M: 2 or 4
  constexpr int MF   = 256 / (WM * 16);// m-frags per wave: 8 or 4
  constexpr int NB_B = BN / 64;        // B issue-blocks per tile

  __shared__ u16 sA0[256 * 64];
  __shared__ u16 sA1[256 * 64];
  __shared__ u16 sB0[BN * 64];
  __shared__ u16 sB1[BN * 64];

  const int tid  = threadIdx.x;
  const int lane = tid & 63;
  const int wave = tid >> 6;
  const int quad = lane >> 4;
  const int l16  = lane & 15;
  const int wm   = wave / WN;
  const int wn   = wave % WN;

  // T1: bijective XCD swizzle (per-z nwg % 8 == 0 for all launches here)
  const int gx  = gridDim.x;
  const int nwg = gx * gridDim.y;
  const int id0 = blockIdx.y * gx + blockIdx.x;
  const int cpx = nwg >> 3;
  const int sid = (id0 & 7) * cpx + (id0 >> 3);
  const int n0  = (sid % gx) * BN;
  const int m0  = (sid / gx) << 8;

  A  += (long)blockIdx.z * sA_;
  Bt += (long)blockIdx.z * sB_;

  // staging: one issue-block = 64 rows x 64 K = 8KB = 512 thr x 16B.
  // thread covers (srow, phys chunk pc); source holds logical chunk pc^(srow&7).
  const int srow = tid >> 3;
  const int pc   = tid & 7;
  const int lc   = pc ^ (srow & 7);
  const u16* gA0 = A  + (long)(m0 + srow) * K + lc * 8;
  const u16* gB0 = Bt + (long)(n0 + srow) * K + lc * 8;
  const int ldst = tid << 3;           // linear LDS dest within block (u16 units)

  fx4 acc[MF][4] = {};

  const int NT = K >> 6;               // even (K % 128 == 0)

#define STG(Sa, Sb, t) do { \
    const long ko_ = (long)(t) << 6; \
    _Pragma("unroll") for (int bb_ = 0; bb_ < 4; ++bb_) \
      async16(&Sa[bb_ * 4096 + ldst], gA0 + (long)(bb_ * 64) * K + ko_); \
    _Pragma("unroll") for (int bb_ = 0; bb_ < NB_B; ++bb_) \
      async16(&Sb[bb_ * 4096 + ldst], gB0 + (long)(bb_ * 64) * K + ko_); \
  } while (0)

  // ds_read + MFMA for one K-tile in buffer (Sa,Sb).
  // logical 16B chunk c = ks*4+quad within the 64-K row; phys = c ^ (row&7),
  // row&7 == l16&7 for every fragment row (bases are multiples of 16).
#define HALF(Sa, Sb) do { \
    _Pragma("unroll") for (int ks_ = 0; ks_ < 2; ++ks_) { \
      const int cko_ = ((((ks_) << 2) | quad) ^ (l16 & 7)) << 3; \
      short8 ar_[MF], br_[4]; \
      _Pragma("unroll") for (int i_ = 0; i_ < MF; ++i_) { \
        const int r_ = wm * (MF * 16) + i_ * 16 + l16; \
        ar_[i_] = *(const short8*)&Sa[(r_ >> 6) * 4096 + (r_ & 63) * 64 + cko_]; \
      } \
      _Pragma("unroll") for (int n_ = 0; n_ < 4; ++n_) { \
        const int r_ = wn * 64 + n_ * 16 + l16; \
        br_[n_] = *(const short8*)&Sb[(r_ >> 6) * 4096 + (r_ & 63) * 64 + cko_]; \
      } \
      __builtin_amdgcn_s_setprio(1); \
      _Pragma("unroll") for (int i_ = 0; i_ < MF; ++i_) \
        _Pragma("unroll") for (int n_ = 0; n_ < 4; ++n_) \
          acc[i_][n_] = __builtin_amdgcn_mfma_f32_16x16x32_bf16( \
              ar_[i_], br_[n_], acc[i_][n_], 0, 0, 0); \
      __builtin_amdgcn_s_setprio(0); \
    } \
  } while (0)

#define TILE_END do { \
    __builtin_amdgcn_sched_barrier(0); \
    asm volatile("s_waitcnt vmcnt(0)"); \
    __builtin_amdgcn_s_barrier(); \
    __builtin_amdgcn_sched_barrier(0); \
  } while (0)

  // prologue: tile 0 into buf0; drain; sync.
  STG(sA0, sB0, 0);
  TILE_END;

  for (int t = 0; t < NT; t += 2) {
    // even tile: read buf0, stage t+1 -> buf1 (t+1 < NT always: NT even)
    STG(sA1, sB1, t + 1);
    HALF(sA0, sB0);
    TILE_END;
    // odd tile: read buf1, stage t+2 -> buf0
    if (t + 2 < NT) STG(sA0, sB0, t + 2);
    HALF(sA1, sB1);
    TILE_END;
  }

  // epilogue: C/D layout col=lane&15, row=quad*4+reg (verified m89/m91)
  float bv[4];
  #pragma unroll
  for (int n = 0; n < 4; ++n)
    bv[n] = BIAS ? bias[n0 + wn * 64 + n * 16 + l16] : 0.0f;

  #pragma unroll
  for (int f = 0; f < MF; ++f) {
    #pragma unroll
    for (int r = 0; r < 4; ++r) {
      const long row  = m0 + wm * (MF * 16) + f * 16 + quad * 4 + r;
      const long base = (long)blockIdx.z * sC_ + row * N + n0 + wn * 64 + l16;
      #pragma unroll
      for (int n = 0; n < 4; ++n) {
        float v = acc[f][n][r] * scale + bv[n];
        if (RELU) { if (v < 0.0f) v = 0.0f; }  // NaN-transparent ReLU
        if (OUTF32) Cf[base + n * 16] = v;
        else        C [base + n * 16] = f2b(v);
      }
    }
  }
#undef STG
#undef HALF
#undef TILE_END
}

// ---------------- masked softmax over row (keys k >= q kept; triu mask) ----------------
__global__ void softmax_kernel(u16* __restrict__ P) {
  const int q = blockIdx.x;
  u16* p = P + ((long)blockIdx.y * S_DIM + q) * S_DIM;
  const int tid = threadIdx.x;
  const int wave = tid >> 6, lane = tid & 63;
  __shared__ float red[4];
  float vals[8];
  float mx = -3.0e38f;
  for (int it = 0; it < 8; ++it) {
    int k = tid + it * 256;
    float v = (k >= q) ? b2f(p[k]) : -3.0e38f;
    vals[it] = v;
    mx = fmaxf(mx, v);
  }
  for (int off = 32; off > 0; off >>= 1)
    mx = fmaxf(mx, __shfl_down(mx, off, 64));
  if (lane == 0) red[wave] = mx;
  __syncthreads();
  mx = fmaxf(fmaxf(red[0], red[1]), fmaxf(red[2], red[3]));
  __syncthreads();
  float sum = 0.0f;
  for (int it = 0; it < 8; ++it) {
    int k = tid + it * 256;
    float e = (k >= q) ? __expf(vals[it] - mx) : 0.0f;
    vals[it] = e;
    sum += e;
  }
  for (int off = 32; off > 0; off >>= 1)
    sum += __shfl_down(sum, off, 64);
  if (lane == 0) red[wave] = sum;
  __syncthreads();
  sum = red[0] + red[1] + red[2] + red[3];
  const float inv = 1.0f / sum;
  for (int it = 0; it < 8; ++it) {
    int k = tid + it * 256;
    p[k] = f2b(vals[it] * inv);
  }
}

extern "C" void kernel_launch(void* const* d_in, const int* in_sizes, int n_in,
                              void* d_out, int out_size, void* d_ws, size_t ws_size,
                              hipStream_t stream) {
  (void)in_sizes; (void)n_in; (void)out_size; (void)ws_size;
  const int*   x   = (const int*)d_in[0];
  const float* emb = (const float*)d_in[1];
  const float* pe  = (const float*)d_in[2];
  const float* wq  = (const float*)d_in[3];
  const float* bq  = (const float*)d_in[4];
  const float* wk  = (const float*)d_in[5];
  const float* bk  = (const float*)d_in[6];
  const float* wv  = (const float*)d_in[7];
  const float* bv  = (const float*)d_in[8];
  const float* w1s = (const float*)d_in[9];
  const float* b1s = (const float*)d_in[10];
  const float* w2s = (const float*)d_in[11];
  const float* b2s = (const float*)d_in[12];
  float* out = (float*)d_out;

  // workspace: bf16 internal activations/weights, ~124 MB.
  // aliases: vT <- q (q dead after scores); mb <- kx+v+P (dead after attention)
  u16* ws  = (u16*)d_ws;
  u16* h   = ws;                               // [8192,1024]
  u16* q   = h  + (long)NTOK * D_DIM;
  u16* kx  = q  + (long)NTOK * D_DIM;
  u16* v   = kx + (long)NTOK * D_DIM;
  u16* P   = v  + (long)NTOK * D_DIM;          // [4][2048,2048]
  u16* wqT = P  + (long)B_DIM * S_DIM * S_DIM; // [1024,1024]
  u16* wkT = wqT + (long)D_DIM * D_DIM;
  u16* wvT = wkT + (long)D_DIM * D_DIM;
  u16* w1T = wvT + (long)D_DIM * D_DIM;        // [4096,1024] per-layer
  u16* w2T = w1T + (long)D_DIM * M_DIM;        // [1024,4096] per-layer
  u16* vT  = q;                                // [4][1024,2048] aliases q
  u16* mb  = kx;                               // [8192,4096] aliases kx,v,P exactly

  const dim3 blk256(256);
  const dim3 blk512(512);
  const dim3 blkT(32, 8);

  // canary prefill of fp32 output (overwritten by final GEMM on success)
  canary_kernel<<<dim3(NTOK), blk256, 0, stream>>>(out);

  // QKV weight transposes (fp32 -> bf16 Bt layout)
  transpose_f_kernel<<<dim3(32, 32), blkT, 0, stream>>>(wq, wqT, 1024, 1024);
  transpose_f_kernel<<<dim3(32, 32), blkT, 0, stream>>>(wk, wkT, 1024, 1024);
  transpose_f_kernel<<<dim3(32, 32), blkT, 0, stream>>>(wv, wvT, 1024, 1024);

  // h = bf16(emb[x] + pos_enc)
  Transformer_33792802685820_kernel<<<dim3(NTOK), blk256, 0, stream>>>(x, emb, pe, h);

  // q,k,v projections (M=8192, N=1024, K=1024): BN=128 -> grid (8,32) = 256 wgs
  gemm256<128, false, true, false><<<dim3(8, 32, 1), blk512, 0, stream>>>(h, wqT, bq, q,  nullptr, NTOK, D_DIM, D_DIM, 1.0f, 0, 0, 0);
  gemm256<128, false, true, false><<<dim3(8, 32, 1), blk512, 0, stream>>>(h, wkT, bk, kx, nullptr, NTOK, D_DIM, D_DIM, 1.0f, 0, 0, 0);
  gemm256<128, false, true, false><<<dim3(8, 32, 1), blk512, 0, stream>>>(h, wvT, bv, v,  nullptr, NTOK, D_DIM, D_DIM, 1.0f, 0, 0, 0);

  // scores = (Q @ K^T) / sqrt(D); BN=256 -> grid (8,8,4), 64 wgs/z
  gemm256<256, false, false, false><<<dim3(8, 8, 4), blk512, 0, stream>>>(q, kx, nullptr, P, nullptr,
      S_DIM, S_DIM, D_DIM, 0.03125f, (long)S_DIM * D_DIM, (long)S_DIM * D_DIM, (long)S_DIM * S_DIM);

  // softmax with triu (self+future) mask, in place
  softmax_kernel<<<dim3(S_DIM, B_DIM), blk256, 0, stream>>>(P);

  // V^T per batch (into dead q), then attn_out = relu(P @ V): BN=128, grid (8,8,4)
  transpose_b_kernel<<<dim3(32, 64, 4), blkT, 0, stream>>>(v, vT, 2048, 1024);
  gemm256<128, true, false, false><<<dim3(8, 8, 4), blk512, 0, stream>>>(P, vT, nullptr, h, nullptr,
      S_DIM, D_DIM, S_DIM, 1.0f, (long)S_DIM * S_DIM, (long)D_DIM * S_DIM, (long)S_DIM * D_DIM);

  // FFN stack; weights transposed per layer (fp32 -> bf16)
  for (int i = 0; i < 4; ++i) {
    transpose_f_kernel<<<dim3(128, 32), blkT, 0, stream>>>(w1s + (long)i * D_DIM * M_DIM, w1T, 1024, 4096);
    transpose_f_kernel<<<dim3(32, 128), blkT, 0, stream>>>(w2s + (long)i * D_DIM * M_DIM, w2T, 4096, 1024);
    // w1: N=4096, BN=256 -> grid (16,32) = 512 wgs
    gemm256<256, true, true, false><<<dim3(16, 32, 1), blk512, 0, stream>>>(
        h, w1T, b1s + i * M_DIM, mb, nullptr, NTOK, M_DIM, D_DIM, 1.0f, 0, 0, 0);
    // w2: N=1024, K=4096, BN=128 -> grid (8,32) = 256 wgs
    if (i == 3)
      gemm256<128, true, true, true><<<dim3(8, 32, 1), blk512, 0, stream>>>(
          mb, w2T, b2s + i * D_DIM, nullptr, out, NTOK, D_DIM, M_DIM, 1.0f, 0, 0, 0);
    else
      gemm256<128, true, true, false><<<dim3(8, 32, 1), blk512, 0, stream>>>(
          mb, w2T, b2s + i * D_DIM, h, nullptr, NTOK, D_DIM, M_DIM, 1.0f, 0, 0, 0);
  }
}

// Round 5
// 1191.533 us; speedup vs baseline: 1.0653x; 1.0653x over previous
//
#include <hip/hip_runtime.h>

// Shapes (fixed for this problem)
#define D_DIM 1024
#define S_DIM 2048
#define B_DIM 4
#define M_DIM 4096
#define NTOK  8192   // B*S

typedef unsigned short u16;
typedef __attribute__((ext_vector_type(8))) short short8;  // 8 bf16 (guide-verified frag type)
typedef __attribute__((ext_vector_type(4))) float fx4;

static __device__ __forceinline__ float b2f(u16 u) {
  union { unsigned int i; float f; } v; v.i = ((unsigned int)u) << 16; return v.f;
}
static __device__ __forceinline__ u16 f2b(float f) {
  union { float f; unsigned int i; } v; v.f = f;
  unsigned int r = v.i + 0x7fffu + ((v.i >> 16) & 1u); // RNE
  return (u16)(r >> 16);
}
// async global->LDS DMA, 16B per lane
static __device__ __forceinline__ void async16(u16* lds, const u16* g) {
  __builtin_amdgcn_global_load_lds(
      (__attribute__((address_space(1))) void*)(u16*)g,
      (__attribute__((address_space(3))) void*)lds, 16, 0, 0);
}

// ---------------- canary: prefill fp32 output with 1.0 (diagnostic) ----------------
__global__ void canary_kernel(float* __restrict__ out) {
  const long i = ((long)blockIdx.x * 256 + threadIdx.x) * 4;
  float4 v = {1.0f, 1.0f, 1.0f, 1.0f};
  *(float4*)(out + i) = v;
}

// ---------------- embedding gather + positional encoding (fp32 in, bf16 out) ----------------
__global__ void Transformer_33792802685820_kernel(
    const int* __restrict__ x, const float* __restrict__ emb,
    const float* __restrict__ pe, u16* __restrict__ h) {
  const int t = blockIdx.x;          // token index 0..NTOK-1
  const int s = t & (S_DIM - 1);     // position within sequence
  const int row = x[t];
  const int d = threadIdx.x * 4;     // 256 threads * 4 = 1024 = D
  float4 e = *(const float4*)(emb + (long)row * D_DIM + d);
  float4 p = *(const float4*)(pe + (long)s * D_DIM + d);
  ushort4 o;
  o.x = f2b(e.x + p.x);
  o.y = f2b(e.y + p.y);
  o.z = f2b(e.z + p.z);
  o.w = f2b(e.w + p.w);
  *(ushort4*)(h + (long)t * D_DIM + d) = o;
}

// ---------------- transpose fp32 -> bf16: out[C][R] = in[R][C] ----------------
__global__ void transpose_f_kernel(
    const float* __restrict__ in, u16* __restrict__ out, int R, int C) {
  __shared__ float tile[32][33];
  const int c0 = blockIdx.x * 32, r0 = blockIdx.y * 32;
  const int tx = threadIdx.x, ty = threadIdx.y; // 32 x 8
  for (int i = ty; i < 32; i += 8)
    tile[i][tx] = in[(long)(r0 + i) * C + (c0 + tx)];
  __syncthreads();
  for (int i = ty; i < 32; i += 8)
    out[(long)(c0 + i) * R + (r0 + tx)] = f2b(tile[tx][i]);
}

// ---------------- transpose bf16 -> bf16, batched over z ----------------
__global__ void transpose_b_kernel(
    const u16* __restrict__ in, u16* __restrict__ out, int R, int C) {
  __shared__ u16 tile[32][33];
  const long zoff = (long)blockIdx.z * R * C;
  const int c0 = blockIdx.x * 32, r0 = blockIdx.y * 32;
  const int tx = threadIdx.x, ty = threadIdx.y; // 32 x 8
  for (int i = ty; i < 32; i += 8)
    tile[i][tx] = in[zoff + (long)(r0 + i) * C + (c0 + tx)];
  __syncthreads();
  for (int i = ty; i < 32; i += 8)
    out[zoff + (long)(c0 + i) * R + (r0 + tx)] = tile[tx][i];
}

// ---------------- 256x256 8-phase MFMA GEMM (faithful m201 skeleton) ----------------
// C = act(scale*A@Bt^T + bias). A [M,K], Bt [N,K] bf16 row-major; M,N %256==0,
// K %128==0 (NT=K/64 even, >=4 in practice), per-z nwg %8==0.
// 512 thr = 8 waves (2M x 4N), per-wave output 128x64. LDS 128 KiB:
// 2 buffers (T0=sA0/sB0 even tiles, T1=sA1/sB1 odd) x {A,B} x 2 kk-halves of
// [256 rows][32 K] (16 KB = 2 DMA issues of 8 KB).
// PHASE (the critical structure, ONE barrier per phase):
//   { ds_read frags (4 A [+4 B at mh0]); stage ONE kk-half (2 async16);
//     [vmcnt at ph4/ph8 only]; s_barrier; lgkmcnt(0); setprio(1); 16 MFMA; setprio(0) }
// One barrier/phase => a wave's next-phase ds_reads overlap peers' MFMA
// (r1/r3 had 2 barriers/phase = lockstep = no overlap, MfmaUtil 23%).
// Counted vmcnt(6) (=3 half-stages in flight) before the ph4/ph8 barrier; never
// vmcnt(0) in steady state (r4's per-tile burst drain = fetch-latency-bound).
// Stage ledger per iteration over tiles (t->T0, t+1->T1), one half per phase:
//   ph1: t+1.A(kk1)->sA1 | ph2: t+2.B(kk0)->sB0 | ph3: t+2.A(kk0)->sA0
//   ph4: t+2.B(kk1)->sB0 +vmcnt(6) | ph5: t+2.A(kk1)->sA0 | ph6: t+3.B(kk0)->sB1
//   ph7: t+3.A(kk0)->sA1 | ph8: t+3.B(kk1)->sB1 +vmcnt(6)
// WAR: each stage target's last reader phase is >=1 barrier earlier (checked all 8).
// RAW: vmcnt(6)@ph4 lands t+1 fully (incl. ph1's stage) before ph5-8 reads T1;
//      vmcnt(6)@ph8 lands t+2 fully before next-iter ph1. Tail (no t+2): ph4 uses
//      vmcnt(0) so ph1's stage lands before ph5-8.
// Swizzle: 16B chunk phys = log ^ (row&3) within each [row][32K] line; DMA source
// pre-swizzled, reads XOR (rule 21). Residual ~4-way conflict (matches m201).
template<bool RELU, bool BIAS, bool OUTF32>
__global__ __launch_bounds__(512) void gemm8p(
    const u16* __restrict__ A, const u16* __restrict__ Bt,
    const float* __restrict__ bias, u16* __restrict__ C, float* __restrict__ Cf,
    int M, int N, int K, float scale, long sA_, long sB_, long sC_) {
  __shared__ u16 sA0[16384];
  __shared__ u16 sA1[16384];
  __shared__ u16 sB0[16384];
  __shared__ u16 sB1[16384];

  const int tid  = threadIdx.x;
  const int lane = tid & 63;
  const int wave = tid >> 6;
  const int quad = lane >> 4;
  const int l16  = lane & 15;
  const int wm   = wave >> 2;   // 0..1
  const int wn   = wave & 3;    // 0..3

  // T1: bijective XCD swizzle (per-z nwg % 8 == 0 for all launches here)
  const int gx  = gridDim.x;
  const int nwg = gx * gridDim.y;
  const int id0 = blockIdx.y * gx + blockIdx.x;
  const int cpx = nwg >> 3;
  const int sid = (id0 & 7) * cpx + (id0 >> 3);
  const int n0  = (sid % gx) << 8;
  const int m0  = (sid / gx) << 8;

  A  += (long)blockIdx.z * sA_;
  Bt += (long)blockIdx.z * sB_;

  // staging: one issue = 512 thr x 16B = 128 rows x 32 K(64B). Source chunk
  // pre-swizzled: lc = pc ^ (srow&3)  (rule 21).
  const int srow = tid >> 2;           // 0..127
  const int pc   = tid & 3;
  const int lc   = pc ^ (srow & 3);
  const u16* gA0 = A  + (long)(m0 + srow) * K + lc * 8;
  const u16* gB0 = Bt + (long)(n0 + srow) * K + lc * 8;
  const int ldst = tid << 3;           // linear LDS dest (u16), 16B/lane

  // read side: phys chunk = quad ^ (row&3), row&3 == l16&3 for all frag rows
  const int cko = ((quad ^ (l16 & 3)) << 3);
  const int baA = wm * 4096 + l16 * 32 + cko;                       // + (mh*64+i*16)*32, + kk*8192
  const int baB = (wn >> 1) * 4096 + (((wn & 1) << 6) + l16) * 32 + cko; // + n*512, + kk*8192

  fx4 acc[8][4] = {};
  short8 ar[4], br[4];

  const int NT = K >> 6;               // even

#define STG_A(S, t, kk) do { \
    const long ko_ = (long)(t) * 64 + (kk) * 32; \
    async16(&S[(kk) * 8192 + ldst],        gA0 + ko_); \
    async16(&S[(kk) * 8192 + 4096 + ldst], gA0 + (long)128 * K + ko_); \
  } while (0)
#define STG_B(S, t, kk) do { \
    const long ko_ = (long)(t) * 64 + (kk) * 32; \
    async16(&S[(kk) * 8192 + ldst],        gB0 + ko_); \
    async16(&S[(kk) * 8192 + 4096 + ldst], gB0 + (long)128 * K + ko_); \
  } while (0)
#define RD_A(S, mh, kk) do { \
    _Pragma("unroll") for (int i_ = 0; i_ < 4; ++i_) \
      ar[i_] = *(const short8*)&S[(kk) * 8192 + baA + ((mh) * 64 + i_ * 16) * 32]; \
  } while (0)
#define RD_B(S, kk) do { \
    _Pragma("unroll") for (int n_ = 0; n_ < 4; ++n_) \
      br[n_] = *(const short8*)&S[(kk) * 8192 + baB + n_ * 512]; \
  } while (0)
#define MM(mh) do { \
    __builtin_amdgcn_s_setprio(1); \
    _Pragma("unroll") for (int i_ = 0; i_ < 4; ++i_) \
      _Pragma("unroll") for (int n_ = 0; n_ < 4; ++n_) \
        acc[(mh) * 4 + i_][n_] = __builtin_amdgcn_mfma_f32_16x16x32_bf16( \
            ar[i_], br[n_], acc[(mh) * 4 + i_][n_], 0, 0, 0); \
    __builtin_amdgcn_s_setprio(0); \
  } while (0)
#define BARR  __builtin_amdgcn_s_barrier()
#define LGKM  asm volatile("s_waitcnt lgkmcnt(0)")
#define VM6   asm volatile("s_waitcnt vmcnt(6)")
#define VM0   asm volatile("s_waitcnt vmcnt(0)")

  // prologue: tile0 (4 halves) + tile1 (3 halves; A(kk1) comes at ph1).
  // vmcnt(6): tile0's 8 loads landed, tile1's 6 outstanding. Then barrier.
  STG_B(sB0, 0, 0); STG_A(sA0, 0, 0); STG_B(sB0, 0, 1); STG_A(sA0, 0, 1);
  STG_B(sB1, 1, 0); STG_A(sA1, 1, 0); STG_B(sB1, 1, 1);
  VM6; BARR;

  for (int t = 0; t < NT; t += 2) {
    const bool more = (t + 2 < NT);
    // ph1: T0(mh0,kk0); stage t+1.A(kk1)
    RD_A(sA0, 0, 0); RD_B(sB0, 0);
    STG_A(sA1, t + 1, 1);
    BARR; LGKM; MM(0);
    // ph2: T0(mh1,kk0); stage t+2.B(kk0)  [T0.B(kk0) retired ph1]
    RD_A(sA0, 1, 0);
    if (more) STG_B(sB0, t + 2, 0);
    BARR; LGKM; MM(1);
    // ph3: T0(mh0,kk1); stage t+2.A(kk0)  [T0.A(kk0) retired ph2]
    RD_A(sA0, 0, 1); RD_B(sB0, 1);
    if (more) STG_A(sA0, t + 2, 0);
    BARR; LGKM; MM(0);
    // ph4: T0(mh1,kk1); stage t+2.B(kk1); counted drain -> t+1 fully landed
    RD_A(sA0, 1, 1);
    if (more) { STG_B(sB0, t + 2, 1); VM6; } else { VM0; }
    BARR; LGKM; MM(1);
    // ph5: T1(mh0,kk0); stage t+2.A(kk1)  [T0.A(kk1) retired ph4]
    RD_A(sA1, 0, 0); RD_B(sB1, 0);
    if (more) STG_A(sA0, t + 2, 1);
    BARR; LGKM; MM(0);
    // ph6: T1(mh1,kk0); stage t+3.B(kk0)  [T1.B(kk0) retired ph5]
    RD_A(sA1, 1, 0);
    if (more) STG_B(sB1, t + 3, 0);
    BARR; LGKM; MM(1);
    // ph7: T1(mh0,kk1); stage t+3.A(kk0)  [T1.A(kk0) retired ph6]
    RD_A(sA1, 0, 1); RD_B(sB1, 1);
    if (more) STG_A(sA1, t + 3, 0);
    BARR; LGKM; MM(0);
    // ph8: T1(mh1,kk1); stage t+3.B(kk1); counted drain -> t+2 fully landed
    RD_A(sA1, 1, 1);
    if (more) { STG_B(sB1, t + 3, 1); VM6; }
    BARR; LGKM; MM(1);
  }

  // epilogue: C/D layout col=lane&15, row=quad*4+reg (verified m89/m91)
  float bv[4];
  #pragma unroll
  for (int n = 0; n < 4; ++n)
    bv[n] = BIAS ? bias[n0 + wn * 64 + n * 16 + l16] : 0.0f;

  #pragma unroll
  for (int f = 0; f < 8; ++f) {
    #pragma unroll
    for (int r = 0; r < 4; ++r) {
      const long row  = m0 + wm * 128 + f * 16 + quad * 4 + r;
      const long base = (long)blockIdx.z * sC_ + row * N + n0 + wn * 64 + l16;
      #pragma unroll
      for (int n = 0; n < 4; ++n) {
        float v = acc[f][n][r] * scale + bv[n];
        if (RELU) { if (v < 0.0f) v = 0.0f; }  // NaN-transparent ReLU
        if (OUTF32) Cf[base + n * 16] = v;
        else        C [base + n * 16] = f2b(v);
      }
    }
  }
#undef STG_A
#undef STG_B
#undef RD_A
#undef RD_B
#undef MM
#undef BARR
#undef LGKM
#undef VM6
#undef VM0
}

// ---------------- masked softmax over row (keys k >= q kept; triu mask) ----------------
__global__ void softmax_kernel(u16* __restrict__ P) {
  const int q = blockIdx.x;
  u16* p = P + ((long)blockIdx.y * S_DIM + q) * S_DIM;
  const int tid = threadIdx.x;
  const int wave = tid >> 6, lane = tid & 63;
  __shared__ float red[4];
  float vals[8];
  float mx = -3.0e38f;
  for (int it = 0; it < 8; ++it) {
    int k = tid + it * 256;
    float v = (k >= q) ? b2f(p[k]) : -3.0e38f;
    vals[it] = v;
    mx = fmaxf(mx, v);
  }
  for (int off = 32; off > 0; off >>= 1)
    mx = fmaxf(mx, __shfl_down(mx, off, 64));
  if (lane == 0) red[wave] = mx;
  __syncthreads();
  mx = fmaxf(fmaxf(red[0], red[1]), fmaxf(red[2], red[3]));
  __syncthreads();
  float sum = 0.0f;
  for (int it = 0; it < 8; ++it) {
    int k = tid + it * 256;
    float e = (k >= q) ? __expf(vals[it] - mx) : 0.0f;
    vals[it] = e;
    sum += e;
  }
  for (int off = 32; off > 0; off >>= 1)
    sum += __shfl_down(sum, off, 64);
  if (lane == 0) red[wave] = sum;
  __syncthreads();
  sum = red[0] + red[1] + red[2] + red[3];
  const float inv = 1.0f / sum;
  for (int it = 0; it < 8; ++it) {
    int k = tid + it * 256;
    p[k] = f2b(vals[it] * inv);
  }
}

extern "C" void kernel_launch(void* const* d_in, const int* in_sizes, int n_in,
                              void* d_out, int out_size, void* d_ws, size_t ws_size,
                              hipStream_t stream) {
  (void)in_sizes; (void)n_in; (void)out_size; (void)ws_size;
  const int*   x   = (const int*)d_in[0];
  const float* emb = (const float*)d_in[1];
  const float* pe  = (const float*)d_in[2];
  const float* wq  = (const float*)d_in[3];
  const float* bq  = (const float*)d_in[4];
  const float* wk  = (const float*)d_in[5];
  const float* bk  = (const float*)d_in[6];
  const float* wv  = (const float*)d_in[7];
  const float* bv  = (const float*)d_in[8];
  const float* w1s = (const float*)d_in[9];
  const float* b1s = (const float*)d_in[10];
  const float* w2s = (const float*)d_in[11];
  const float* b2s = (const float*)d_in[12];
  float* out = (float*)d_out;

  // workspace: bf16 internal activations/weights, ~124 MB.
  // aliases: vT <- q (q dead after scores); mb <- kx+v+P (dead after attention)
  u16* ws  = (u16*)d_ws;
  u16* h   = ws;                               // [8192,1024]
  u16* q   = h  + (long)NTOK * D_DIM;
  u16* kx  = q  + (long)NTOK * D_DIM;
  u16* v   = kx + (long)NTOK * D_DIM;
  u16* P   = v  + (long)NTOK * D_DIM;          // [4][2048,2048]
  u16* wqT = P  + (long)B_DIM * S_DIM * S_DIM; // [1024,1024]
  u16* wkT = wqT + (long)D_DIM * D_DIM;
  u16* wvT = wkT + (long)D_DIM * D_DIM;
  u16* w1T = wvT + (long)D_DIM * D_DIM;        // [4096,1024] per-layer
  u16* w2T = w1T + (long)D_DIM * M_DIM;        // [1024,4096] per-layer
  u16* vT  = q;                                // [4][1024,2048] aliases q
  u16* mb  = kx;                               // [8192,4096] aliases kx,v,P exactly

  const dim3 blk256(256);
  const dim3 blk512(512);
  const dim3 blkT(32, 8);

  // canary prefill of fp32 output (overwritten by final GEMM on success)
  canary_kernel<<<dim3(NTOK), blk256, 0, stream>>>(out);

  // QKV weight transposes (fp32 -> bf16 Bt layout)
  transpose_f_kernel<<<dim3(32, 32), blkT, 0, stream>>>(wq, wqT, 1024, 1024);
  transpose_f_kernel<<<dim3(32, 32), blkT, 0, stream>>>(wk, wkT, 1024, 1024);
  transpose_f_kernel<<<dim3(32, 32), blkT, 0, stream>>>(wv, wvT, 1024, 1024);

  // h = bf16(emb[x] + pos_enc)
  Transformer_33792802685820_kernel<<<dim3(NTOK), blk256, 0, stream>>>(x, emb, pe, h);

  // q,k,v projections (M=8192, N=1024, K=1024): grid (4,32) = 128 wgs
  gemm8p<false, true, false><<<dim3(4, 32, 1), blk512, 0, stream>>>(h, wqT, bq, q,  nullptr, NTOK, D_DIM, D_DIM, 1.0f, 0, 0, 0);
  gemm8p<false, true, false><<<dim3(4, 32, 1), blk512, 0, stream>>>(h, wkT, bk, kx, nullptr, NTOK, D_DIM, D_DIM, 1.0f, 0, 0, 0);
  gemm8p<false, true, false><<<dim3(4, 32, 1), blk512, 0, stream>>>(h, wvT, bv, v,  nullptr, NTOK, D_DIM, D_DIM, 1.0f, 0, 0, 0);

  // scores = (Q @ K^T) / sqrt(D); grid (8,8,4), 64 wgs/z
  gemm8p<false, false, false><<<dim3(8, 8, 4), blk512, 0, stream>>>(q, kx, nullptr, P, nullptr,
      S_DIM, S_DIM, D_DIM, 0.03125f, (long)S_DIM * D_DIM, (long)S_DIM * D_DIM, (long)S_DIM * S_DIM);

  // softmax with triu (self+future) mask, in place
  softmax_kernel<<<dim3(S_DIM, B_DIM), blk256, 0, stream>>>(P);

  // V^T per batch (into dead q), then attn_out = relu(P @ V): grid (4,8,4)
  transpose_b_kernel<<<dim3(32, 64, 4), blkT, 0, stream>>>(v, vT, 2048, 1024);
  gemm8p<true, false, false><<<dim3(4, 8, 4), blk512, 0, stream>>>(P, vT, nullptr, h, nullptr,
      S_DIM, D_DIM, S_DIM, 1.0f, (long)S_DIM * S_DIM, (long)D_DIM * S_DIM, (long)S_DIM * D_DIM);

  // FFN stack; weights transposed per layer (fp32 -> bf16)
  for (int i = 0; i < 4; ++i) {
    transpose_f_kernel<<<dim3(128, 32), blkT, 0, stream>>>(w1s + (long)i * D_DIM * M_DIM, w1T, 1024, 4096);
    transpose_f_kernel<<<dim3(32, 128), blkT, 0, stream>>>(w2s + (long)i * D_DIM * M_DIM, w2T, 4096, 1024);
    // w1: N=4096 -> grid (16,32) = 512 wgs
    gemm8p<true, true, false><<<dim3(16, 32, 1), blk512, 0, stream>>>(
        h, w1T, b1s + i * M_DIM, mb, nullptr, NTOK, M_DIM, D_DIM, 1.0f, 0, 0, 0);
    // w2: N=1024, K=4096 -> grid (4,32) = 128 wgs
    if (i == 3)
      gemm8p<true, true, true><<<dim3(4, 32, 1), blk512, 0, stream>>>(
          mb, w2T, b2s + i * D_DIM, nullptr, out, NTOK, D_DIM, M_DIM, 1.0f, 0, 0, 0);
    else
      gemm8p<true, true, false><<<dim3(4, 32, 1), blk512, 0, stream>>>(
          mb, w2T, b2s + i * D_DIM, h, nullptr, NTOK, D_DIM, M_DIM, 1.0f, 0, 0, 0);
  }
}

// Round 6
// 1158.572 us; speedup vs baseline: 1.0956x; 1.0284x over previous
//
#include <hip/hip_runtime.h>

// Shapes (fixed for this problem)
#define D_DIM 1024
#define S_DIM 2048
#define B_DIM 4
#define M_DIM 4096
#define NTOK  8192   // B*S

typedef unsigned short u16;
typedef __attribute__((ext_vector_type(8))) short short8;  // 8 bf16 (guide-verified frag type)
typedef __attribute__((ext_vector_type(4))) float fx4;

static __device__ __forceinline__ float b2f(u16 u) {
  union { unsigned int i; float f; } v; v.i = ((unsigned int)u) << 16; return v.f;
}
static __device__ __forceinline__ u16 f2b(float f) {
  union { float f; unsigned int i; } v; v.f = f;
  unsigned int r = v.i + 0x7fffu + ((v.i >> 16) & 1u); // RNE
  return (u16)(r >> 16);
}
// async global->LDS DMA, 16B per lane
static __device__ __forceinline__ void async16(u16* lds, const u16* g) {
  __builtin_amdgcn_global_load_lds(
      (__attribute__((address_space(1))) void*)(u16*)g,
      (__attribute__((address_space(3))) void*)lds, 16, 0, 0);
}

// ---------------- canary: prefill fp32 output with 1.0 (diagnostic) ----------------
__global__ void canary_kernel(float* __restrict__ out) {
  const long i = ((long)blockIdx.x * 256 + threadIdx.x) * 4;
  float4 v = {1.0f, 1.0f, 1.0f, 1.0f};
  *(float4*)(out + i) = v;
}

// ---------------- embedding gather + positional encoding (fp32 in, bf16 out) ----------------
__global__ void Transformer_33792802685820_kernel(
    const int* __restrict__ x, const float* __restrict__ emb,
    const float* __restrict__ pe, u16* __restrict__ h) {
  const int t = blockIdx.x;          // token index 0..NTOK-1
  const int s = t & (S_DIM - 1);     // position within sequence
  const int row = x[t];
  const int d = threadIdx.x * 4;     // 256 threads * 4 = 1024 = D
  float4 e = *(const float4*)(emb + (long)row * D_DIM + d);
  float4 p = *(const float4*)(pe + (long)s * D_DIM + d);
  ushort4 o;
  o.x = f2b(e.x + p.x);
  o.y = f2b(e.y + p.y);
  o.z = f2b(e.z + p.z);
  o.w = f2b(e.w + p.w);
  *(ushort4*)(h + (long)t * D_DIM + d) = o;
}

// ---------------- transpose fp32 -> bf16: out[C][R] = in[R][C] ----------------
__global__ void transpose_f_kernel(
    const float* __restrict__ in, u16* __restrict__ out, int R, int C) {
  __shared__ float tile[32][33];
  const int c0 = blockIdx.x * 32, r0 = blockIdx.y * 32;
  const int tx = threadIdx.x, ty = threadIdx.y; // 32 x 8
  for (int i = ty; i < 32; i += 8)
    tile[i][tx] = in[(long)(r0 + i) * C + (c0 + tx)];
  __syncthreads();
  for (int i = ty; i < 32; i += 8)
    out[(long)(c0 + i) * R + (r0 + tx)] = f2b(tile[tx][i]);
}

// ---------------- transpose bf16 -> bf16, batched over z ----------------
__global__ void transpose_b_kernel(
    const u16* __restrict__ in, u16* __restrict__ out, int R, int C) {
  __shared__ u16 tile[32][33];
  const long zoff = (long)blockIdx.z * R * C;
  const int c0 = blockIdx.x * 32, r0 = blockIdx.y * 32;
  const int tx = threadIdx.x, ty = threadIdx.y; // 32 x 8
  for (int i = ty; i < 32; i += 8)
    tile[i][tx] = in[zoff + (long)(r0 + i) * C + (c0 + tx)];
  __syncthreads();
  for (int i = ty; i < 32; i += 8)
    out[zoff + (long)(c0 + i) * R + (r0 + tx)] = tile[tx][i];
}

// ---------------- legacy 128x128 MFMA GEMM (QKV: proven ~26us at 512 wgs) ----------------
template<bool RELU, bool BIAS, bool OUTF32>
__global__ void gemm_bt(
    const u16* __restrict__ A, const u16* __restrict__ Bt,
    const float* __restrict__ bias, u16* __restrict__ C, float* __restrict__ Cf,
    int M, int N, int K, float scale, long sA, long sB, long sC) {
  __shared__ u16 As[128 * 32];
  __shared__ u16 Bs[128 * 32];
  const int tid  = threadIdx.x;
  const int wave = tid >> 6;
  const int lane = tid & 63;
  const int quad = lane >> 4;
  const int l16  = lane & 15;
  const int wm = (wave & 1) << 6;
  const int wn = (wave >> 1) << 6;
  A  += (long)blockIdx.z * sA;
  Bt += (long)blockIdx.z * sB;
  const int m0 = blockIdx.y << 7;
  const int n0 = blockIdx.x << 7;

  const int row_a = tid >> 2;
  const int c4    = (tid & 3) << 3;
  const u16* gA = A  + (long)(m0 + row_a) * K + c4;
  const u16* gB = Bt + (long)(n0 + row_a) * K + c4;
  u16* lA = &As[tid * 8];
  u16* lB = &Bs[tid * 8];

  fx4 acc[4][4] = {};

  for (int k0 = 0; k0 < K; k0 += 32) {
    async16(lA,            gA + k0);
    async16(lA + 64 * 32,  gA + (long)64 * K + k0);
    async16(lB,            gB + k0);
    async16(lB + 64 * 32,  gB + (long)64 * K + k0);
    __syncthreads();
    short8 af[4], bfv[4];
    #pragma unroll
    for (int i = 0; i < 4; ++i) {
      af[i]  = *(const short8*)&As[(wm + i * 16 + l16) * 32 + quad * 8];
      bfv[i] = *(const short8*)&Bs[(wn + i * 16 + l16) * 32 + quad * 8];
    }
    __syncthreads();
    #pragma unroll
    for (int mi = 0; mi < 4; ++mi)
      #pragma unroll
      for (int ni = 0; ni < 4; ++ni)
        acc[mi][ni] = __builtin_amdgcn_mfma_f32_16x16x32_bf16(
            af[mi], bfv[ni], acc[mi][ni], 0, 0, 0);
  }

  float bv[4];
  #pragma unroll
  for (int ni = 0; ni < 4; ++ni)
    bv[ni] = BIAS ? bias[n0 + wn + ni * 16 + l16] : 0.0f;

  #pragma unroll
  for (int mi = 0; mi < 4; ++mi) {
    #pragma unroll
    for (int r = 0; r < 4; ++r) {
      const long row = m0 + wm + mi * 16 + quad * 4 + r;
      const long base = row * N + n0 + wn + l16;
      #pragma unroll
      for (int ni = 0; ni < 4; ++ni) {
        float v = acc[mi][ni][r] * scale + bv[ni];
        if (RELU) { if (v < 0.0f) v = 0.0f; }
        if (OUTF32) Cf[(long)blockIdx.z * sC + base + ni * 16] = v;
        else        C [(long)blockIdx.z * sC + base + ni * 16] = f2b(v);
      }
    }
  }
}

#define BARR  __builtin_amdgcn_s_barrier()
#define LGKM  asm volatile("s_waitcnt lgkmcnt(0)")
#define VM8   asm volatile("s_waitcnt vmcnt(8)")
#define VM6   asm volatile("s_waitcnt vmcnt(6)")
#define VM3   asm volatile("s_waitcnt vmcnt(3)")
#define VM0   asm volatile("s_waitcnt vmcnt(0)")

// ---------------- 256x256 8-phase MFMA GEMM (r5, passed; w1 + scores) ----------------
// See r5 notes: 8 waves 2Mx4N, phases (kk,mh), one barrier/phase, VM6@ph4/ph8.
template<bool RELU, bool BIAS, bool OUTF32>
__global__ __launch_bounds__(512) void gemm8p(
    const u16* __restrict__ A, const u16* __restrict__ Bt,
    const float* __restrict__ bias, u16* __restrict__ C, float* __restrict__ Cf,
    int M, int N, int K, float scale, long sA_, long sB_, long sC_) {
  __shared__ u16 sA0[16384];
  __shared__ u16 sA1[16384];
  __shared__ u16 sB0[16384];
  __shared__ u16 sB1[16384];

  const int tid  = threadIdx.x;
  const int lane = tid & 63;
  const int wave = tid >> 6;
  const int quad = lane >> 4;
  const int l16  = lane & 15;
  const int wm   = wave >> 2;   // 0..1
  const int wn   = wave & 3;    // 0..3

  const int gx  = gridDim.x;
  const int nwg = gx * gridDim.y;
  const int id0 = blockIdx.y * gx + blockIdx.x;
  const int cpx = nwg >> 3;
  const int sid = (id0 & 7) * cpx + (id0 >> 3);
  const int n0  = (sid % gx) << 8;
  const int m0  = (sid / gx) << 8;

  A  += (long)blockIdx.z * sA_;
  Bt += (long)blockIdx.z * sB_;

  const int srow = tid >> 2;           // 0..127
  const int pc   = tid & 3;
  const int lc   = pc ^ (srow & 3);
  const u16* gA0 = A  + (long)(m0 + srow) * K + lc * 8;
  const u16* gB0 = Bt + (long)(n0 + srow) * K + lc * 8;
  const int ldst = tid << 3;

  const int cko = ((quad ^ (l16 & 3)) << 3);
  const int baA = wm * 4096 + l16 * 32 + cko;
  const int baB = (wn >> 1) * 4096 + (((wn & 1) << 6) + l16) * 32 + cko;

  fx4 acc[8][4] = {};
  short8 ar[4], br[4];

  const int NT = K >> 6;               // even

#define STG_A(S, t, kk) do { \
    const long ko_ = (long)(t) * 64 + (kk) * 32; \
    async16(&S[(kk) * 8192 + ldst],        gA0 + ko_); \
    async16(&S[(kk) * 8192 + 4096 + ldst], gA0 + (long)128 * K + ko_); \
  } while (0)
#define STG_B(S, t, kk) do { \
    const long ko_ = (long)(t) * 64 + (kk) * 32; \
    async16(&S[(kk) * 8192 + ldst],        gB0 + ko_); \
    async16(&S[(kk) * 8192 + 4096 + ldst], gB0 + (long)128 * K + ko_); \
  } while (0)
#define RD_A(S, mh, kk) do { \
    _Pragma("unroll") for (int i_ = 0; i_ < 4; ++i_) \
      ar[i_] = *(const short8*)&S[(kk) * 8192 + baA + ((mh) * 64 + i_ * 16) * 32]; \
  } while (0)
#define RD_B(S, kk) do { \
    _Pragma("unroll") for (int n_ = 0; n_ < 4; ++n_) \
      br[n_] = *(const short8*)&S[(kk) * 8192 + baB + n_ * 512]; \
  } while (0)
#define MM(mh) do { \
    __builtin_amdgcn_s_setprio(1); \
    _Pragma("unroll") for (int i_ = 0; i_ < 4; ++i_) \
      _Pragma("unroll") for (int n_ = 0; n_ < 4; ++n_) \
        acc[(mh) * 4 + i_][n_] = __builtin_amdgcn_mfma_f32_16x16x32_bf16( \
            ar[i_], br[n_], acc[(mh) * 4 + i_][n_], 0, 0, 0); \
    __builtin_amdgcn_s_setprio(0); \
  } while (0)

  STG_B(sB0, 0, 0); STG_A(sA0, 0, 0); STG_B(sB0, 0, 1); STG_A(sA0, 0, 1);
  STG_B(sB1, 1, 0); STG_A(sA1, 1, 0); STG_B(sB1, 1, 1);
  VM6; BARR;

  for (int t = 0; t < NT; t += 2) {
    const bool more = (t + 2 < NT);
    RD_A(sA0, 0, 0); RD_B(sB0, 0);
    STG_A(sA1, t + 1, 1);
    BARR; LGKM; MM(0);
    RD_A(sA0, 1, 0);
    if (more) STG_B(sB0, t + 2, 0);
    BARR; LGKM; MM(1);
    RD_A(sA0, 0, 1); RD_B(sB0, 1);
    if (more) STG_A(sA0, t + 2, 0);
    BARR; LGKM; MM(0);
    RD_A(sA0, 1, 1);
    if (more) { STG_B(sB0, t + 2, 1); VM6; } else { VM0; }
    BARR; LGKM; MM(1);
    RD_A(sA1, 0, 0); RD_B(sB1, 0);
    if (more) STG_A(sA0, t + 2, 1);
    BARR; LGKM; MM(0);
    RD_A(sA1, 1, 0);
    if (more) STG_B(sB1, t + 3, 0);
    BARR; LGKM; MM(1);
    RD_A(sA1, 0, 1); RD_B(sB1, 1);
    if (more) STG_A(sA1, t + 3, 0);
    BARR; LGKM; MM(0);
    RD_A(sA1, 1, 1);
    if (more) { STG_B(sB1, t + 3, 1); VM6; }
    BARR; LGKM; MM(1);
  }

  float bv[4];
  #pragma unroll
  for (int n = 0; n < 4; ++n)
    bv[n] = BIAS ? bias[n0 + wn * 64 + n * 16 + l16] : 0.0f;

  #pragma unroll
  for (int f = 0; f < 8; ++f) {
    #pragma unroll
    for (int r = 0; r < 4; ++r) {
      const long row  = m0 + wm * 128 + f * 16 + quad * 4 + r;
      const long base = (long)blockIdx.z * sC_ + row * N + n0 + wn * 64 + l16;
      #pragma unroll
      for (int n = 0; n < 4; ++n) {
        float v = acc[f][n][r] * scale + bv[n];
        if (RELU) { if (v < 0.0f) v = 0.0f; }  // NaN-transparent ReLU
        if (OUTF32) Cf[base + n * 16] = v;
        else        C [base + n * 16] = f2b(v);
      }
    }
  }
#undef STG_A
#undef STG_B
#undef RD_A
#undef RD_B
#undef MM
}

// ---------------- 256x128 8-phase MFMA GEMM (full-grid variant for w2/PV) ----------------
// 8 waves as 4M x 2N (wave out 64x128... rows 64, cols 64 via wn in {0,1}).
// LDS 96 KiB: sA dbuf 2x32KB (2 kk-halves x [2x128 rows][32K]), sB dbuf 2x16KB
// (2 kk-halves x [128 rows][32K], 1 DMA issue per half).
// Phases (kk, nh): RD_A 4 frags at nh0 (reused nh1), RD_B 2 frags each phase,
// MFMA 4m x 2n = 8. Stage ledger (3 issues per even/odd phase pair, checked
// WAR/RAW case-by-case): ph1: t+1.B1; ph2: t+2.A0 +VM8; ph3: t+2.B0;
// ph4: t+2.A1 +VM8; ph5: t+2.B1; ph6: t+3.A0 +VM8; ph7: t+3.B0; ph8: t+3.A1 +VM8.
// Uniform vmcnt(8) at even phases (= newest 5 slots outstanding) guarantees every
// region drained >=1 phase before its first read. Prologue: 11 issues + VM8.
// Tail (last iter): VM6@ph2, VM3@ph4, VM0@ph6 (derived from residual ledger).
template<bool RELU, bool BIAS, bool OUTF32>
__global__ __launch_bounds__(512) void gemm8n(
    const u16* __restrict__ A, const u16* __restrict__ Bt,
    const float* __restrict__ bias, u16* __restrict__ C, float* __restrict__ Cf,
    int M, int N, int K, float scale, long sA_, long sB_, long sC_) {
  __shared__ u16 sA0[16384];
  __shared__ u16 sA1[16384];
  __shared__ u16 sB0[8192];
  __shared__ u16 sB1[8192];

  const int tid  = threadIdx.x;
  const int lane = tid & 63;
  const int wave = tid >> 6;
  const int quad = lane >> 4;
  const int l16  = lane & 15;
  const int wm   = wave >> 1;   // 0..3
  const int wn   = wave & 1;    // 0..1

  const int gx  = gridDim.x;
  const int nwg = gx * gridDim.y;
  const int id0 = blockIdx.y * gx + blockIdx.x;
  const int cpx = nwg >> 3;
  const int sid = (id0 & 7) * cpx + (id0 >> 3);
  const int n0  = (sid % gx) << 7;   // BN = 128
  const int m0  = (sid / gx) << 8;   // BM = 256

  A  += (long)blockIdx.z * sA_;
  Bt += (long)blockIdx.z * sB_;

  const int srow = tid >> 2;           // 0..127
  const int pc   = tid & 3;
  const int lc   = pc ^ (srow & 3);
  const u16* gA0 = A  + (long)(m0 + srow) * K + lc * 8;
  const u16* gB0 = Bt + (long)(n0 + srow) * K + lc * 8;
  const int ldst = tid << 3;

  const int cko = ((quad ^ (l16 & 3)) << 3);
  // A row = wm*64 + i*16 + l16: blk = wm>>1, in-blk = (wm&1)*64 + i*16 + l16
  const int baA = (wm >> 1) * 4096 + (((wm & 1) << 6) + l16) * 32 + cko;
  // B row = wn*64 + n*16 + l16
  const int baB = ((wn << 6) + l16) * 32 + cko;

  fx4 acc[4][4] = {};
  short8 ar[4], br[2];

  const int NT = K >> 6;               // even

#define STG_A(S, t, kk) do { \
    const long ko_ = (long)(t) * 64 + (kk) * 32; \
    async16(&S[(kk) * 8192 + ldst],        gA0 + ko_); \
    async16(&S[(kk) * 8192 + 4096 + ldst], gA0 + (long)128 * K + ko_); \
  } while (0)
#define STG_B(S, t, kk) \
    async16(&S[(kk) * 4096 + ldst], gB0 + (long)(t) * 64 + (kk) * 32)
#define RD_A(S, kk) do { \
    _Pragma("unroll") for (int i_ = 0; i_ < 4; ++i_) \
      ar[i_] = *(const short8*)&S[(kk) * 8192 + baA + i_ * 512]; \
  } while (0)
#define RD_B(S, kk, nh) do { \
    _Pragma("unroll") for (int n_ = 0; n_ < 2; ++n_) \
      br[n_] = *(const short8*)&S[(kk) * 4096 + baB + ((nh) * 2 + n_) * 512]; \
  } while (0)
#define MM(nh) do { \
    __builtin_amdgcn_s_setprio(1); \
    _Pragma("unroll") for (int i_ = 0; i_ < 4; ++i_) \
      _Pragma("unroll") for (int n_ = 0; n_ < 2; ++n_) \
        acc[i_][(nh) * 2 + n_] = __builtin_amdgcn_mfma_f32_16x16x32_bf16( \
            ar[i_], br[n_], acc[i_][(nh) * 2 + n_], 0, 0, 0); \
    __builtin_amdgcn_s_setprio(0); \
  } while (0)

  // prologue: t0 full (A0,B0,A1,B1) + t1 minus B1 (A0,B0,A1) = 11 issues
  STG_A(sA0, 0, 0); STG_B(sB0, 0, 0); STG_A(sA0, 0, 1); STG_B(sB0, 0, 1);
  STG_A(sA1, 1, 0); STG_B(sB1, 1, 0); STG_A(sA1, 1, 1);
  VM8; BARR;   // t0.A0,B0 landed

  for (int t = 0; t < NT; t += 2) {
    const bool more = (t + 2 < NT);
    // ph1: T0 kk0 nh0; stage t+1.B1
    RD_A(sA0, 0); RD_B(sB0, 0, 0);
    STG_B(sB1, t + 1, 1);
    BARR; LGKM; MM(0);
    // ph2: T0 kk0 nh1; stage t+2.A0
    RD_B(sB0, 0, 1);
    if (more) { STG_A(sA0, t + 2, 0); VM8; } else { VM6; }
    BARR; LGKM; MM(1);
    // ph3: T0 kk1 nh0; stage t+2.B0
    RD_A(sA0, 1); RD_B(sB0, 1, 0);
    if (more) STG_B(sB0, t + 2, 0);
    BARR; LGKM; MM(0);
    // ph4: T0 kk1 nh1; stage t+2.A1
    RD_B(sB0, 1, 1);
    if (more) { STG_A(sA0, t + 2, 1); VM8; } else { VM3; }
    BARR; LGKM; MM(1);
    // ph5: T1 kk0 nh0; stage t+2.B1
    RD_A(sA1, 0); RD_B(sB1, 0, 0);
    if (more) STG_B(sB0, t + 2, 1);
    BARR; LGKM; MM(0);
    // ph6: T1 kk0 nh1; stage t+3.A0
    RD_B(sB1, 0, 1);
    if (more) { STG_A(sA1, t + 3, 0); VM8; } else { VM0; }
    BARR; LGKM; MM(1);
    // ph7: T1 kk1 nh0; stage t+3.B0
    RD_A(sA1, 1); RD_B(sB1, 1, 0);
    if (more) STG_B(sB1, t + 3, 0);
    BARR; LGKM; MM(0);
    // ph8: T1 kk1 nh1; stage t+3.A1
    RD_B(sB1, 1, 1);
    if (more) { STG_A(sA1, t + 3, 1); VM8; }
    BARR; LGKM; MM(1);
  }

  float bv[4];
  #pragma unroll
  for (int n = 0; n < 4; ++n)
    bv[n] = BIAS ? bias[n0 + wn * 64 + n * 16 + l16] : 0.0f;

  #pragma unroll
  for (int f = 0; f < 4; ++f) {
    #pragma unroll
    for (int r = 0; r < 4; ++r) {
      const long row  = m0 + wm * 64 + f * 16 + quad * 4 + r;
      const long base = (long)blockIdx.z * sC_ + row * N + n0 + wn * 64 + l16;
      #pragma unroll
      for (int n = 0; n < 4; ++n) {
        float v = acc[f][n][r] * scale + bv[n];
        if (RELU) { if (v < 0.0f) v = 0.0f; }  // NaN-transparent ReLU
        if (OUTF32) Cf[base + n * 16] = v;
        else        C [base + n * 16] = f2b(v);
      }
    }
  }
#undef STG_A
#undef STG_B
#undef RD_A
#undef RD_B
#undef MM
}

// ---------------- masked softmax (k >= q kept); masked prefix written as zeros ----------------
__global__ void softmax_kernel(u16* __restrict__ P) {
  const int q = blockIdx.x;
  u16* p = P + ((long)blockIdx.y * S_DIM + q) * S_DIM;
  const int tid = threadIdx.x;
  const int wave = tid >> 6, lane = tid & 63;
  const int it0 = q >> 8;            // 256-blocks below q: fully masked
  __shared__ float red[4];
  float vals[8];
  // masked prefix: zero-write only (skip read+exp); PV consumes P densely
  for (int it = 0; it < it0; ++it) p[tid + it * 256] = 0;
  float mx = -3.0e38f;
  for (int it = it0; it < 8; ++it) {
    int k = tid + it * 256;
    float v = (k >= q) ? b2f(p[k]) : -3.0e38f;
    vals[it] = v;
    mx = fmaxf(mx, v);
  }
  for (int off = 32; off > 0; off >>= 1)
    mx = fmaxf(mx, __shfl_down(mx, off, 64));
  if (lane == 0) red[wave] = mx;
  __syncthreads();
  mx = fmaxf(fmaxf(red[0], red[1]), fmaxf(red[2], red[3]));
  __syncthreads();
  float sum = 0.0f;
  for (int it = it0; it < 8; ++it) {
    int k = tid + it * 256;
    float e = (k >= q) ? __expf(vals[it] - mx) : 0.0f;
    vals[it] = e;
    sum += e;
  }
  for (int off = 32; off > 0; off >>= 1)
    sum += __shfl_down(sum, off, 64);
  if (lane == 0) red[wave] = sum;
  __syncthreads();
  sum = red[0] + red[1] + red[2] + red[3];
  const float inv = 1.0f / sum;
  for (int it = it0; it < 8; ++it) {
    int k = tid + it * 256;
    p[k] = f2b(vals[it] * inv);
  }
}

extern "C" void kernel_launch(void* const* d_in, const int* in_sizes, int n_in,
                              void* d_out, int out_size, void* d_ws, size_t ws_size,
                              hipStream_t stream) {
  (void)in_sizes; (void)n_in; (void)out_size; (void)ws_size;
  const int*   x   = (const int*)d_in[0];
  const float* emb = (const float*)d_in[1];
  const float* pe  = (const float*)d_in[2];
  const float* wq  = (const float*)d_in[3];
  const float* bq  = (const float*)d_in[4];
  const float* wk  = (const float*)d_in[5];
  const float* bk  = (const float*)d_in[6];
  const float* wv  = (const float*)d_in[7];
  const float* bv  = (const float*)d_in[8];
  const float* w1s = (const float*)d_in[9];
  const float* b1s = (const float*)d_in[10];
  const float* w2s = (const float*)d_in[11];
  const float* b2s = (const float*)d_in[12];
  float* out = (float*)d_out;

  // workspace: bf16 internal activations/weights, ~124 MB.
  u16* ws  = (u16*)d_ws;
  u16* h   = ws;                               // [8192,1024]
  u16* q   = h  + (long)NTOK * D_DIM;
  u16* kx  = q  + (long)NTOK * D_DIM;
  u16* v   = kx + (long)NTOK * D_DIM;
  u16* P   = v  + (long)NTOK * D_DIM;          // [4][2048,2048]
  u16* wqT = P  + (long)B_DIM * S_DIM * S_DIM; // [1024,1024]
  u16* wkT = wqT + (long)D_DIM * D_DIM;
  u16* wvT = wkT + (long)D_DIM * D_DIM;
  u16* w1T = wvT + (long)D_DIM * D_DIM;        // [4096,1024] per-layer
  u16* w2T = w1T + (long)D_DIM * M_DIM;        // [1024,4096] per-layer
  u16* vT  = q;                                // [4][1024,2048] aliases q
  u16* mb  = kx;                               // [8192,4096] aliases kx,v,P exactly

  const dim3 blk256(256);
  const dim3 blk512(512);
  const dim3 blkT(32, 8);

  canary_kernel<<<dim3(NTOK), blk256, 0, stream>>>(out);

  transpose_f_kernel<<<dim3(32, 32), blkT, 0, stream>>>(wq, wqT, 1024, 1024);
  transpose_f_kernel<<<dim3(32, 32), blkT, 0, stream>>>(wk, wkT, 1024, 1024);
  transpose_f_kernel<<<dim3(32, 32), blkT, 0, stream>>>(wv, wvT, 1024, 1024);

  Transformer_33792802685820_kernel<<<dim3(NTOK), blk256, 0, stream>>>(x, emb, pe, h);

  // q,k,v projections: legacy 128^2 at 512 wgs (full grid, proven ~26us each)
  gemm_bt<false, true, false><<<dim3(8, 64, 1), blk256, 0, stream>>>(h, wqT, bq, q,  nullptr, NTOK, D_DIM, D_DIM, 1.0f, 0, 0, 0);
  gemm_bt<false, true, false><<<dim3(8, 64, 1), blk256, 0, stream>>>(h, wkT, bk, kx, nullptr, NTOK, D_DIM, D_DIM, 1.0f, 0, 0, 0);
  gemm_bt<false, true, false><<<dim3(8, 64, 1), blk256, 0, stream>>>(h, wvT, bv, v,  nullptr, NTOK, D_DIM, D_DIM, 1.0f, 0, 0, 0);

  // scores = (Q @ K^T) / sqrt(D): 256^2, (8,8,4) = 256 wgs
  gemm8p<false, false, false><<<dim3(8, 8, 4), blk512, 0, stream>>>(q, kx, nullptr, P, nullptr,
      S_DIM, S_DIM, D_DIM, 0.03125f, (long)S_DIM * D_DIM, (long)S_DIM * D_DIM, (long)S_DIM * S_DIM);

  softmax_kernel<<<dim3(S_DIM, B_DIM), blk256, 0, stream>>>(P);

  // V^T per batch, then attn_out = relu(P @ V): 256x128, (8,8,4) = 256 wgs (full grid)
  transpose_b_kernel<<<dim3(32, 64, 4), blkT, 0, stream>>>(v, vT, 2048, 1024);
  gemm8n<true, false, false><<<dim3(8, 8, 4), blk512, 0, stream>>>(P, vT, nullptr, h, nullptr,
      S_DIM, D_DIM, S_DIM, 1.0f, (long)S_DIM * S_DIM, (long)D_DIM * S_DIM, (long)S_DIM * D_DIM);

  // FFN stack
  for (int i = 0; i < 4; ++i) {
    transpose_f_kernel<<<dim3(128, 32), blkT, 0, stream>>>(w1s + (long)i * D_DIM * M_DIM, w1T, 1024, 4096);
    transpose_f_kernel<<<dim3(32, 128), blkT, 0, stream>>>(w2s + (long)i * D_DIM * M_DIM, w2T, 4096, 1024);
    // w1: N=4096, 256^2 -> (16,32) = 512 wgs
    gemm8p<true, true, false><<<dim3(16, 32, 1), blk512, 0, stream>>>(
        h, w1T, b1s + i * M_DIM, mb, nullptr, NTOK, M_DIM, D_DIM, 1.0f, 0, 0, 0);
    // w2: N=1024, K=4096, 256x128 -> (8,32) = 256 wgs (full grid, was 128)
    if (i == 3)
      gemm8n<true, true, true><<<dim3(8, 32, 1), blk512, 0, stream>>>(
          mb, w2T, b2s + i * D_DIM, nullptr, out, NTOK, D_DIM, M_DIM, 1.0f, 0, 0, 0);
    else
      gemm8n<true, true, false><<<dim3(8, 32, 1), blk512, 0, stream>>>(
          mb, w2T, b2s + i * D_DIM, h, nullptr, NTOK, D_DIM, M_DIM, 1.0f, 0, 0, 0);
  }
}